// Round 10
// baseline (222.059 us; speedup 1.0000x reference)
//
#include <hip/hip_runtime.h>

#define XS     256
#define XS2    65536
#define LAT    10
#define BR     8             // rows per bin group
#define NG     (XS / BR)     // 32 groups per image
#define NBINS  512           // B(16) * NG(32)
#define SBB    512           // scatter blocks per image (b uniform per block)
#define IPBMAX 784           // staged items capacity (>= IPB=782)
#define CAPB   64            // LDS slots per local bin (= wave size; mean ~24.4)
#define BINCAP 15360         // per-bin global record capacity (mean ~12.5k)
#define SPLIT  2             // accum sub-blocks per bin
#define CELLW  128           // 2x2 cells: 128 column-pairs
#define QS     256.0f        // fixed-point scale 2^8
#define INVQS  (1.0f / 256.0f)

// async global->LDS 16B granule (gfx950). Whole-wave issues only.
#define GLOAD_LDS(g, l) __builtin_amdgcn_global_load_lds(                      \
    (const __attribute__((address_space(1))) unsigned*)(g),                    \
    (__attribute__((address_space(3))) unsigned*)(l), 16, 0, 0)

__device__ __forceinline__ void lds_add_u64(unsigned long long* p,
                                            unsigned long long v) {
    __hip_atomic_fetch_add(p, v, __ATOMIC_RELAXED, __HIP_MEMORY_SCOPE_WORKGROUP);
}

// pack 4 signed 16-bit fixed-point fields into a u64 (carry-exact under add
// while every partial field-sum stays within +-2^15).
__device__ __forceinline__ unsigned long long pack4(int q0, int q1, int q2, int q3) {
    return (unsigned long long)((long long)q0 + ((long long)q1 << 16) +
                                ((long long)q2 << 32) + ((long long)q3 << 48));
}

// ---------------------------------------------------------------------------
// Coordinate math (fmaf-pinned; identical across all paths).
// ---------------------------------------------------------------------------
__device__ __forceinline__ void compute_rc(const float* __restrict__ flow,
                                           const int* __restrict__ inds,
                                           const float* __restrict__ rot,
                                           const float* __restrict__ shifts,
                                           int b, int n, int N,
                                           int& r, int& c, float& f0, float& f1) {
    const float* R = rot + b * 9;
    float r00 = R[0], r01 = R[1], r02 = R[2];
    float r10 = R[3], r11 = R[4], r12 = R[5];
    float s0 = shifts[b * 2 + 0], s1 = shifts[b * 2 + 1];
    size_t fo = ((size_t)b * N + n) * 3;
    float fw0 = flow[fo + 0], fw1 = flow[fo + 1], fw2 = flow[fo + 2];
    float v0 = (float)inds[n * 3 + 2] - 128.0f + fw0;
    float v1 = (float)inds[n * 3 + 1] - 128.0f + fw1;
    float v2 = (float)inds[n * 3 + 0] - 128.0f + fw2;
    float p0 = fmaf(v0, r00, fmaf(v1, r01, fmaf(v2, r02, 128.0f - s0)));
    float p1 = fmaf(v0, r10, fmaf(v1, r11, fmaf(v2, r12, 128.0f - s1)));
    float cs0 = p1, cs1 = p0;     // c_sampling = (coords[...,1], coords[...,0])
    float ff0 = floorf(cs0), ff1 = floorf(cs1);
    r = (int)ff0; c = (int)ff1;
    f0 = cs0 - ff0; f1 = cs1 - ff1;
}

// JAX .at[].add semantics: negative indices wrap once, then OOB dropped.
// Integer quantum atomic: order-free -> bit-deterministic final grid.
__device__ __forceinline__ void corner_q(int* __restrict__ Q, int rr, int cc, float a) {
    if (rr >= -XS && rr < XS && cc >= -XS && cc < XS) {
        int q = __float2int_rn(a * QS);
        if (q) atomicAdd(&Q[((rr + XS) & (XS - 1)) * XS + ((cc + XS) & (XS - 1))], q);
    }
}

// fast path iff rows r, r+1 both valid and don't wrap-split.
__device__ __forceinline__ bool is_fast(int r) {
    return (r >= -XS) && (r <= XS - 2) && (r != -1);
}

// Record: low = rig[0:2] wc[3:10] cv0[11] cv1[12] q0[13:21] q1[22:30];
// high = amp f32 bits. Overflow fallback produces EXACTLY the integer quanta
// the accum path would, added to qimg with i32 atomics -> path-independent sums.
__device__ __forceinline__ void rec_fallback_q(unsigned long long rec, int bin,
                                               int* __restrict__ qimg) {
    unsigned w = (unsigned)rec;
    float amp = __uint_as_float((unsigned)(rec >> 32));
    int b = bin >> 5, g = bin & 31;
    int rig = w & 7, wc = (w >> 3) & 255;
    int wr = g * BR + rig;
    float f0 = (float)((w >> 13) & 511) * (1.0f / 512.0f);
    float f1 = (float)((w >> 22) & 511) * (1.0f / 512.0f);
    float g0 = 1.0f - f0, g1 = 1.0f - f1;
    int* Q = qimg + (size_t)b * XS2;
    if (w & (1u << 11)) {
        int q00 = __float2int_rn(amp * g0 * g1 * QS);
        int q10 = __float2int_rn(amp * f0 * g1 * QS);
        if (q00) atomicAdd(&Q[wr * XS + wc], q00);
        if (q10) atomicAdd(&Q[(wr + 1) * XS + wc], q10);
    }
    if (w & (1u << 12)) {
        int wc1 = (wc + 1) & 255;
        int q01 = __float2int_rn(amp * g0 * f1 * QS);
        int q11 = __float2int_rn(amp * f0 * f1 * QS);
        if (q01) atomicAdd(&Q[wr * XS + wc1], q01);
        if (q11) atomicAdd(&Q[(wr + 1) * XS + wc1], q11);
    }
}

// ---------------------------------------------------------------------------
// Workspace init (no hipMemsetAsync: keeps the capture graph kernel-only).
// ---------------------------------------------------------------------------
__global__ void init_kernel(uint4* __restrict__ p, int n4) {
    int i = blockIdx.x * blockDim.x + threadIdx.x;
    int stride = gridDim.x * blockDim.x;
    uint4 z; z.x = 0u; z.y = 0u; z.z = 0u; z.w = 0u;
    for (; i < n4; i += stride) p[i] = z;
}

// ---------------------------------------------------------------------------
// MLP body: one block computes one (b,l) output with a fixed-order tree
// reduction -> no atomics, bit-deterministic.
// ---------------------------------------------------------------------------
__device__ __forceinline__ void mlp_block(const float* __restrict__ x,
                                          const float* __restrict__ w1,
                                          float* __restrict__ hraw, int id,
                                          float* red) {
    int t = threadIdx.x;
    int b = id / LAT, l = id - b * LAT;
    const float* xb = x + (size_t)b * XS2;
    float acc = 0.0f;
#pragma unroll 8
    for (int j = 0; j < 256; j++) {
        int e = j * 256 + t;
        acc += xb[e] * w1[(size_t)e * LAT + l];
    }
#pragma unroll
    for (int off = 32; off > 0; off >>= 1) acc += __shfl_down(acc, off);
    if ((t & 63) == 0) red[t >> 6] = acc;
    __syncthreads();
    if (t == 0) hraw[b * LAT + l] = (red[0] + red[1]) + (red[2] + red[3]);
}

// ---------------------------------------------------------------------------
// Stage validDw dwords from gsrc into lds: whole-wave 16B async granules via
// global_load_lds (LDS dest = wave-uniform base + lane*16), ragged tail via
// scalar dword copy. No OOB (never reads past validDw), no partial-wave DMA.
// ---------------------------------------------------------------------------
__device__ __forceinline__ void stageArr(const unsigned* __restrict__ gsrc,
                                         unsigned* lds, int validDw, int t) {
    int nG16   = validDw >> 2;       // full 16B granules available
    int asyncG = nG16 & ~63;         // whole-wave granules only
    unsigned* dstBase = lds + ((t >> 6) << 8);     // w*1024B (wave-uniform)
    for (int k = 0; (t & ~63) + k * 256 < asyncG; k++)
        GLOAD_LDS(gsrc + (size_t)(t + k * 256) * 4, dstBase + k * 1024);
    for (int d = (asyncG << 2) + t; d < validDw; d += 256)
        lds[d] = gsrc[d];
}

// ---------------------------------------------------------------------------
// Pass 1 (fused MLP+hist+place). MLP blocks FIRST (overlap the scatter).
// Scatter blocks are per-image (SBB=512) so b is block-uniform.
// NEW: the block's whole input slice (flow/inds/values, ~22KB) is staged
// via async global_load_lds up front — ONE latency exposure per block
// instead of per-item serial global loads (VGPR=16..24 across R7-R9 proved
// hipcc re-sinks register prefetches; LDS staging is structural, it can't).
// Compute loop is then pure LDS + VALU. Phase 2: 32 lanes reserve global
// ranges. Phase 3: branchless per-wave bin copy (cn<=64=wave size).
// ---------------------------------------------------------------------------
__global__ void __launch_bounds__(256, 4)
place_kernel(const float* __restrict__ flow,
             const float* __restrict__ values,
             const int* __restrict__ inds,
             const float* __restrict__ rot,
             const float* __restrict__ shifts,
             const float* __restrict__ x,
             const float* __restrict__ w1,
             float* __restrict__ hraw,
             unsigned* __restrict__ gcursor,
             unsigned long long* __restrict__ recs,
             int* __restrict__ qimg,
             int N, int IPB, int B) {
    __shared__ unsigned long long slots[NG * CAPB];   // 16384 B
    __shared__ unsigned sFlow[IPBMAX * 3];            // 9408 B
    __shared__ unsigned sInds[IPBMAX * 3];            // 9408 B
    __shared__ unsigned sVal[IPBMAX];                 // 3136 B
    __shared__ unsigned lcnt[NG];
    __shared__ unsigned lbase[NG];
    __shared__ float red4[4];

    int t = threadIdx.x;

    if (blockIdx.x < (unsigned)(B * LAT)) {     // ---- fused MLP path (FIRST) ----
        mlp_block(x, w1, hraw, blockIdx.x, red4);
        return;
    }
    int bid = blockIdx.x - B * LAT;
    int b = bid >> 9;                 // SBB = 512 blocks per image
    int j = bid & (SBB - 1);

    int s = b * N + j * IPB;
    int e = min(s + IPB, (b + 1) * N);
    int cnt = e - s;
    int n0 = s - b * N;               // first local item index within image

    // ---- phase 0: async-stage the block's input slice into LDS ----
    stageArr((const unsigned*)flow + (size_t)s * 3,  sFlow, cnt * 3, t);
    stageArr((const unsigned*)inds + (size_t)n0 * 3, sInds, cnt * 3, t);
    stageArr((const unsigned*)values + n0,           sVal,  cnt,     t);
    if (t < NG) lcnt[t] = 0;
    __syncthreads();                  // drains vmcnt (DMA) + lgkmcnt

    // hoisted per-image constants (b uniform -> scalar regs)
    const float* R = rot + b * 9;
    float r00 = R[0], r01 = R[1], r02 = R[2];
    float r10 = R[3], r11 = R[4], r12 = R[5];
    float s0 = shifts[b * 2 + 0], s1 = shifts[b * 2 + 1];
    int* Q = qimg + (size_t)b * XS2;

    // ---- phase 1: LDS-local compute + place record at final LDS slot ----
    for (int li = t; li < cnt; li += 256) {
        float fw0 = __uint_as_float(sFlow[li * 3 + 0]);
        float fw1 = __uint_as_float(sFlow[li * 3 + 1]);
        float fw2 = __uint_as_float(sFlow[li * 3 + 2]);
        float v0 = (float)(int)sInds[li * 3 + 2] - 128.0f + fw0;
        float v1 = (float)(int)sInds[li * 3 + 1] - 128.0f + fw1;
        float v2 = (float)(int)sInds[li * 3 + 0] - 128.0f + fw2;
        float amp = __uint_as_float(sVal[li]);
        float p0 = fmaf(v0, r00, fmaf(v1, r01, fmaf(v2, r02, 128.0f - s0)));
        float p1 = fmaf(v0, r10, fmaf(v1, r11, fmaf(v2, r12, 128.0f - s1)));
        float ff0 = floorf(p1), ff1 = floorf(p0);
        int r = (int)ff0, c = (int)ff1;
        float f0 = p1 - ff0, f1 = p0 - ff1;
        if (is_fast(r)) {
            int wr = (r + XS) & (XS - 1);
            int wc = c & (XS - 1);
            unsigned cv0 = (c >= -XS && c < XS) ? 1u : 0u;
            unsigned cv1 = (c + 1 >= -XS && c + 1 < XS) ? 1u : 0u;
            unsigned q0 = min(511u, (unsigned)(f0 * 512.0f + 0.5f));
            unsigned q1 = min(511u, (unsigned)(f1 * 512.0f + 0.5f));
            unsigned word = (unsigned)(wr & 7) | ((unsigned)wc << 3) |
                            (cv0 << 11) | (cv1 << 12) | (q0 << 13) | (q1 << 22);
            unsigned long long rec =
                ((unsigned long long)__float_as_uint(amp) << 32) | word;
            int local = wr >> 3;                        // [0,32)
            unsigned r2 = atomicAdd(&lcnt[local], 1u);
            if (r2 < CAPB) slots[local * CAPB + r2] = rec;
            else rec_fallback_q(rec, b * NG + local, qimg);  // cap overflow (rare)
        } else {
            float g0 = 1.0f - f0, g1 = 1.0f - f1;
            corner_q(Q, r,     c,     amp * g0 * g1);
            corner_q(Q, r + 1, c,     amp * f0 * g1);
            corner_q(Q, r + 1, c + 1, amp * f0 * f1);
            corner_q(Q, r,     c + 1, amp * g0 * f1);
        }
    }
    __syncthreads();

    // ---- phase 2 (lanes 0..31): reserve global ranges ----
    if (t < NG) {
        unsigned cn = min(lcnt[t], (unsigned)CAPB);   // stored records only
        lbase[t] = cn ? atomicAdd(&gcursor[b * NG + t], cn) : 0u;
        lcnt[t] = cn;
    }
    __syncthreads();

    // ---- phase 3: branchless per-wave bin copy (1 predicated store/bin) ----
    int wid = t >> 6, lane = t & 63;
    unsigned cns[8], gbs[8];
#pragma unroll
    for (int z = 0; z < 8; z++) {
        int lb = wid + (z << 2);
        cns[z] = lcnt[lb]; gbs[z] = lbase[lb];
    }
#pragma unroll
    for (int z = 0; z < 8; z++) {
        int lb = wid + (z << 2);
        if ((unsigned)lane < cns[z]) {
            unsigned long long rc = slots[lb * CAPB + lane];
            unsigned idx = gbs[z] + lane;
            int bing = b * NG + lb;
            if (idx < BINCAP) recs[(size_t)bing * BINCAP + idx] = rc;
            else rec_fallback_q(rc, bing, qimg);   // global overflow (rare)
        }
    }
}

// ---------------------------------------------------------------------------
// Pass 2: dual-parity 2x2 u64 cells -> exactly ONE ds_add_u64 per record.
// All-integer accumulation -> order-free -> deterministic.
// ---------------------------------------------------------------------------
__global__ void __launch_bounds__(256)
accum_kernel(const unsigned long long* __restrict__ recs,
             const unsigned* __restrict__ gcursor,
             float* __restrict__ reps,
             float* __restrict__ aprons, int B) {
    int bin = blockIdx.x >> 1, sp = blockIdx.x & 1;   // SPLIT=2
    int b = bin >> 5, g = bin & 31;
    __shared__ unsigned long long teven[BR * CELLW];  // 8 KB
    __shared__ unsigned long long todd[BR * CELLW];   // 8 KB
    int t = threadIdx.x;
    for (int k = t; k < BR * CELLW; k += 256) { teven[k] = 0ull; todd[k] = 0ull; }
    __syncthreads();

    unsigned cnt = min(gcursor[bin], (unsigned)BINCAP);
    unsigned lo = (unsigned)(((unsigned long long)cnt * sp) / SPLIT);
    unsigned hi = (unsigned)(((unsigned long long)cnt * (sp + 1)) / SPLIT);
    const unsigned long long* rb = recs + (size_t)bin * BINCAP;

    for (unsigned i = lo + t; i < hi; i += 256) {
        unsigned long long rc = rb[i];
        unsigned w = (unsigned)rc;
        float amp = __uint_as_float((unsigned)(rc >> 32));
        int rig = w & 7, wc = (w >> 3) & 255;
        float f0 = (float)((w >> 13) & 511) * (1.0f / 512.0f);
        float f1 = (float)((w >> 22) & 511) * (1.0f / 512.0f);
        float g0 = 1.0f - f0, g1 = 1.0f - f1;
        bool cv0 = (w >> 11) & 1, cv1 = (w >> 12) & 1;
        int q00 = cv0 ? __float2int_rn(amp * g0 * g1 * QS) : 0;  // (r,   cLo)
        int q10 = cv0 ? __float2int_rn(amp * f0 * g1 * QS) : 0;  // (r+1, cLo)
        int q01 = cv1 ? __float2int_rn(amp * g0 * f1 * QS) : 0;  // (r,   cHi)
        int q11 = cv1 ? __float2int_rn(amp * f0 * f1 * QS) : 0;  // (r+1, cHi)
        unsigned long long inc = pack4(q00, q10, q01, q11);
        unsigned long long* tile = (wc & 1) ? todd : teven;
        lds_add_u64(&tile[rig * CELLW + (wc >> 1)], inc);
    }
    __syncthreads();

    // flush: thread t = column c; carry r1-parts downward; row 8 -> apron.
    int c = t;
    int je = c >> 1;                                       // even tile cell
    int jo = (c & 1) ? (c >> 1) : (((c + 254) & 255) >> 1);// odd tile cell
    bool e_lo = (c & 1) == 0;   // even tile: this column is cLo (fields 0,1)
    bool o_lo = (c & 1) == 1;   // odd tile:  this column is cLo (fields 0,1)
    float* rep = reps + ((size_t)sp * B + b) * XS2;
    float carry = 0.0f;
#pragma unroll
    for (int rig = 0; rig < BR; rig++) {
        long long se = (long long)teven[rig * CELLW + je];
        int e0 = (int)(short)(se & 0xffff); se = (se - e0) >> 16;
        int e1 = (int)(short)(se & 0xffff); se = (se - e1) >> 16;
        int e2 = (int)(short)(se & 0xffff); se = (se - e2) >> 16;
        int e3 = (int)se;
        long long so = (long long)todd[rig * CELLW + jo];
        int o0 = (int)(short)(so & 0xffff); so = (so - o0) >> 16;
        int o1 = (int)(short)(so & 0xffff); so = (so - o1) >> 16;
        int o2 = (int)(short)(so & 0xffff); so = (so - o2) >> 16;
        int o3 = (int)so;
        float r0 = (e_lo ? (float)e0 : (float)e2) + (o_lo ? (float)o0 : (float)o2);
        float r1 = (e_lo ? (float)e1 : (float)e3) + (o_lo ? (float)o1 : (float)o3);
        rep[(g * BR + rig) * XS + c] = (carry + r0) * INVQS;
        carry = r1;
    }
    aprons[((size_t)bin * 2 + sp) * XS + c] = carry * INVQS;
}

// ---------------------------------------------------------------------------
// Fallback direct-scatter (tiny ws / unexpected shapes) — integer atomics.
// ---------------------------------------------------------------------------
__global__ void scatter_kernel(const float* __restrict__ flow,
                               const float* __restrict__ values,
                               const int* __restrict__ inds,
                               const float* __restrict__ rot,
                               const float* __restrict__ shifts,
                               int* __restrict__ qimg, int N) {
    int b = blockIdx.y;
    int n = blockIdx.x * blockDim.x + threadIdx.x;
    if (n >= N) return;
    int r, c; float f0, f1;
    compute_rc(flow, inds, rot, shifts, b, n, N, r, c, f0, f1);
    float amp = values[n];
    float g0 = 1.0f - f0, g1 = 1.0f - f1;
    int* Q = qimg + (size_t)b * XS2;
    corner_q(Q, r,     c,     amp * g0 * g1);
    corner_q(Q, r + 1, c,     amp * f0 * g1);
    corner_q(Q, r + 1, c + 1, amp * f0 * f1);
    corner_q(Q, r,     c + 1, amp * g0 * f1);
}

__global__ void mlp_kernel(const float* __restrict__ x,
                           const float* __restrict__ w1,
                           float* __restrict__ hraw) {
    __shared__ float red4[4];
    mlp_block(x, w1, hraw, blockIdx.x, red4);
}

// ---------------------------------------------------------------------------
// Fused combine + separable 3x3 blur + per-batch affine.
// S[row] = qimg/QS + rep0 + rep1 (+ aprons at row = 8k, k>=1).
// ---------------------------------------------------------------------------
__device__ __forceinline__ float S_load(const int* __restrict__ qimg,
                                        const float* __restrict__ reps,
                                        const float* __restrict__ aprons,
                                        int B, int b, int row, int c, int fast) {
    size_t o = (size_t)b * XS2 + row * XS + c;
    float v = (float)qimg[o] * INVQS;
    if (fast) {
        v += reps[o] + reps[(size_t)B * XS2 + o];
        if (row > 0 && (row & 7) == 0) {
            size_t bin = (size_t)b * NG + ((row >> 3) - 1);
            v += aprons[bin * 2 * XS + c] + aprons[(bin * 2 + 1) * XS + c];
        }
    }
    return v;
}

__global__ void blur_kernel(const int* __restrict__ qimg,
                            const float* __restrict__ reps,
                            const float* __restrict__ aprons,
                            const float* __restrict__ hraw,
                            const float* __restrict__ b1,
                            const float* __restrict__ w2,
                            const float* __restrict__ b2,
                            float* __restrict__ out, int B, int fast) {
    int b = blockIdx.y, r = blockIdx.x, c = threadIdx.x;
    float av = b2[0], bv = b2[1];
#pragma unroll
    for (int l = 0; l < LAT; l++) {
        float h = hraw[b * LAT + l] + b1[l];
        h = h > 0.0f ? h : 0.0f;
        av += h * w2[l * 2 + 0];
        bv += h * w2[l * 2 + 1];
    }
    const float g   = 0.6065306597126334f;   // exp(-0.5)
    const float inv = 1.0f / (1.0f + 2.0f * g);
    float up  = (r > 0)      ? S_load(qimg, reps, aprons, B, b, r - 1, c, fast) : 0.0f;
    float mid =                S_load(qimg, reps, aprons, B, b, r,     c, fast);
    float dn  = (r < XS - 1) ? S_load(qimg, reps, aprons, B, b, r + 1, c, fast) : 0.0f;
    float v = (g * (up + dn) + mid) * inv;
    __shared__ float row[XS + 2];
    row[c + 1] = v;
    if (c == 0) { row[0] = 0.0f; row[XS + 1] = 0.0f; }
    __syncthreads();
    float hh = (g * (row[c] + row[c + 2]) + v) * inv;
    out[(size_t)b * XS2 + (size_t)r * XS + c] = av * hh + bv;
}

extern "C" void kernel_launch(void* const* d_in, const int* in_sizes, int n_in,
                              void* d_out, int out_size, void* d_ws, size_t ws_size,
                              hipStream_t stream) {
    const float* flow   = (const float*)d_in[0];
    const float* x      = (const float*)d_in[1];
    const float* values = (const float*)d_in[2];
    const float* rot    = (const float*)d_in[3];
    const float* shifts = (const float*)d_in[4];
    const float* w1     = (const float*)d_in[5];
    const float* b1     = (const float*)d_in[6];
    const float* w2     = (const float*)d_in[7];
    const float* b2     = (const float*)d_in[8];
    const int*   inds   = (const int*)d_in[9];

    int N = in_sizes[2];          // values: (N,)
    int B = in_sizes[4] / 2;      // shifts: (B,2)
    int IPB = (N + SBB - 1) / SBB;   // items per scatter block (per image)

    // workspace layout: qimg | hraw(256 f32) | gcursor(NBINS) | recs | reps | aprons
    size_t imgElems = (size_t)B * XS2;
    int*      qimg    = (int*)d_ws;
    float*    hraw    = (float*)(qimg + imgElems);        // 256 floats reserved
    unsigned* gcursor = (unsigned*)(hraw + 256);          // NBINS (512)
    unsigned long long* recs = (unsigned long long*)(gcursor + NBINS);  // NBINS*BINCAP
    float*    reps    = (float*)(recs + (size_t)NBINS * BINCAP);        // 2*B*XS2
    float*    aprons  = reps + 2 * imgElems;              // NBINS*2*XS
    size_t needed = (size_t)((char*)(aprons + (size_t)NBINS * 2 * XS) - (char*)d_ws);

    bool fast = (B * NG == NBINS) && (ws_size >= needed) && (IPB <= IPBMAX);

    // zero qimg + hraw + gcursor (bytes divisible by 16)
    int n4 = (int)((imgElems * sizeof(int) + 1024 + NBINS * 4) / 16);
    init_kernel<<<512, 256, 0, stream>>>((uint4*)d_ws, n4);

    if (fast) {
        place_kernel<<<B * LAT + B * SBB, 256, 0, stream>>>(flow, values, inds, rot,
                                                            shifts, x, w1, hraw,
                                                            gcursor, recs, qimg,
                                                            N, IPB, B);
        accum_kernel<<<NBINS * SPLIT, 256, 0, stream>>>(recs, gcursor, reps, aprons, B);
    } else {
        dim3 g1((N + 255) / 256, B);
        scatter_kernel<<<g1, 256, 0, stream>>>(flow, values, inds, rot, shifts, qimg, N);
        mlp_kernel<<<B * LAT, 256, 0, stream>>>(x, w1, hraw);
    }

    dim3 g3(XS, B);
    blur_kernel<<<g3, XS, 0, stream>>>(qimg, reps, aprons, hraw, b1, w2, b2,
                                       (float*)d_out, B, fast ? 1 : 0);
}

// Round 11
// 205.938 us; speedup vs baseline: 1.0783x; 1.0783x over previous
//
#include <hip/hip_runtime.h>

#define XS     256
#define XS2    65536
#define LAT    10
#define BR     8             // rows per bin group
#define NG     (XS / BR)     // 32 groups per image
#define NBINS  512           // B(16) * NG(32)
#define P1     4096          // scatter blocks (IPB=1563 <= 1568 slots)
#define K_MAX  7             // items per thread
#define SLOTS  1792          // K_MAX*256 fixed item slots
#define RECSL  1568          // max valid records per block (>= IPB)
#define BINCAP 15360         // per-bin record capacity (mean ~12.5k)
#define SPLIT  2             // accum sub-blocks per bin
#define CELLW  128           // 2x2 cells: 128 column-pairs
#define QS     256.0f        // fixed-point scale 2^8
#define INVQS  (1.0f / 256.0f)
#define ZB     512           // init: zeroing blocks
#define TB     256           // init: w1-transpose blocks (XS2/256)

__device__ __forceinline__ void lds_add_u64(unsigned long long* p,
                                            unsigned long long v) {
    __hip_atomic_fetch_add(p, v, __ATOMIC_RELAXED, __HIP_MEMORY_SCOPE_WORKGROUP);
}

// pack 4 signed 16-bit fixed-point fields into a u64 (carry-exact under add
// while every partial field-sum stays within +-2^15).
__device__ __forceinline__ unsigned long long pack4(int q0, int q1, int q2, int q3) {
    return (unsigned long long)((long long)q0 + ((long long)q1 << 16) +
                                ((long long)q2 << 32) + ((long long)q3 << 48));
}

// ---------------------------------------------------------------------------
// Coordinate math (fmaf-pinned; identical across all paths).
// ---------------------------------------------------------------------------
__device__ __forceinline__ void compute_rc(const float* __restrict__ flow,
                                           const int* __restrict__ inds,
                                           const float* __restrict__ rot,
                                           const float* __restrict__ shifts,
                                           int b, int n, int N,
                                           int& r, int& c, float& f0, float& f1) {
    const float* R = rot + b * 9;
    float r00 = R[0], r01 = R[1], r02 = R[2];
    float r10 = R[3], r11 = R[4], r12 = R[5];
    float s0 = shifts[b * 2 + 0], s1 = shifts[b * 2 + 1];
    size_t fo = ((size_t)b * N + n) * 3;
    float fw0 = flow[fo + 0], fw1 = flow[fo + 1], fw2 = flow[fo + 2];
    float v0 = (float)inds[n * 3 + 2] - 128.0f + fw0;
    float v1 = (float)inds[n * 3 + 1] - 128.0f + fw1;
    float v2 = (float)inds[n * 3 + 0] - 128.0f + fw2;
    float p0 = fmaf(v0, r00, fmaf(v1, r01, fmaf(v2, r02, 128.0f - s0)));
    float p1 = fmaf(v0, r10, fmaf(v1, r11, fmaf(v2, r12, 128.0f - s1)));
    float cs0 = p1, cs1 = p0;     // c_sampling = (coords[...,1], coords[...,0])
    float ff0 = floorf(cs0), ff1 = floorf(cs1);
    r = (int)ff0; c = (int)ff1;
    f0 = cs0 - ff0; f1 = cs1 - ff1;
}

// JAX .at[].add semantics: negative indices wrap once, then OOB dropped.
// Integer quantum atomic: order-free -> bit-deterministic final grid.
__device__ __forceinline__ void corner_q(int* __restrict__ Q, int rr, int cc, float a) {
    if (rr >= -XS && rr < XS && cc >= -XS && cc < XS) {
        int q = __float2int_rn(a * QS);
        if (q) atomicAdd(&Q[((rr + XS) & (XS - 1)) * XS + ((cc + XS) & (XS - 1))], q);
    }
}

// fast path iff rows r, r+1 both valid and don't wrap-split.
__device__ __forceinline__ bool is_fast(int r) {
    return (r >= -XS) && (r <= XS - 2) && (r != -1);
}

// Record: low = rig[0:2] wc[3:10] cv0[11] cv1[12] q0[13:21] q1[22:30];
// high = amp f32 bits. Overflow fallback produces EXACTLY the integer quanta
// the accum path would, added to qimg with i32 atomics -> path-independent sums.
__device__ __forceinline__ void rec_fallback_q(unsigned long long rec, int bin,
                                               int* __restrict__ qimg) {
    unsigned w = (unsigned)rec;
    float amp = __uint_as_float((unsigned)(rec >> 32));
    int b = bin >> 5, g = bin & 31;
    int rig = w & 7, wc = (w >> 3) & 255;
    int wr = g * BR + rig;
    float f0 = (float)((w >> 13) & 511) * (1.0f / 512.0f);
    float f1 = (float)((w >> 22) & 511) * (1.0f / 512.0f);
    float g0 = 1.0f - f0, g1 = 1.0f - f1;
    int* Q = qimg + (size_t)b * XS2;
    if (w & (1u << 11)) {
        int q00 = __float2int_rn(amp * g0 * g1 * QS);
        int q10 = __float2int_rn(amp * f0 * g1 * QS);
        if (q00) atomicAdd(&Q[wr * XS + wc], q00);
        if (q10) atomicAdd(&Q[(wr + 1) * XS + wc], q10);
    }
    if (w & (1u << 12)) {
        int wc1 = (wc + 1) & 255;
        int q01 = __float2int_rn(amp * g0 * f1 * QS);
        int q11 = __float2int_rn(amp * f0 * f1 * QS);
        if (q01) atomicAdd(&Q[wr * XS + wc1], q01);
        if (q11) atomicAdd(&Q[(wr + 1) * XS + wc1], q11);
    }
}

// ---------------------------------------------------------------------------
// Workspace init + w1 transpose (no hipMemsetAsync: graph stays kernel-only).
// Blocks [0,ZB): zero qimg/hraw/gcursor. Blocks [ZB,ZB+TB): transpose w1
// (65536x10 -> 10x65536) via LDS tile so the fused MLP reads COALESCED
// (raw w1 reads are stride-40B: ~40 L1 transactions per wave-load, which
// contended with scatter blocks' address units on 160 CUs). Exact copy ->
// determinism unaffected.
// ---------------------------------------------------------------------------
__global__ void init_kernel(uint4* __restrict__ p, int n4,
                            const float* __restrict__ w1,
                            float* __restrict__ w1T, int doT) {
    __shared__ float tile[256 * LAT];   // 10 KB
    int t = threadIdx.x;
    if (blockIdx.x < ZB) {
        int i = blockIdx.x * 256 + t;
        int stride = ZB * 256;
        uint4 z; z.x = 0u; z.y = 0u; z.z = 0u; z.w = 0u;
        for (; i < n4; i += stride) p[i] = z;
        return;
    }
    if (!doT) return;
    int e0 = (int)(blockIdx.x - ZB) * 256;
    const float* src = w1 + (size_t)e0 * LAT;
    for (int d = t; d < 256 * LAT; d += 256) tile[d] = src[d];
    __syncthreads();
#pragma unroll
    for (int l = 0; l < LAT; l++)
        w1T[(size_t)l * XS2 + e0 + t] = tile[t * LAT + l];
}

// ---------------------------------------------------------------------------
// MLP body (fast path): coalesced w1T reads. One block per (b,l) output,
// fixed-order tree reduction -> no atomics, bit-deterministic. FP sum order
// per thread identical to the strided version (same e sequence).
// ---------------------------------------------------------------------------
__device__ __forceinline__ void mlp_block(const float* __restrict__ x,
                                          const float* __restrict__ w1T,
                                          float* __restrict__ hraw, int id) {
    int t = threadIdx.x;
    int b = id / LAT, l = id - b * LAT;
    const float* xb = x + (size_t)b * XS2;
    const float* wl = w1T + (size_t)l * XS2;
    float acc = 0.0f;
#pragma unroll 8
    for (int j = 0; j < 256; j++) {
        int e = j * 256 + t;
        acc += xb[e] * wl[e];
    }
#pragma unroll
    for (int off = 32; off > 0; off >>= 1) acc += __shfl_down(acc, off);
    __shared__ float red[4];
    if ((t & 63) == 0) red[t >> 6] = acc;
    __syncthreads();
    if (t == 0) hraw[b * LAT + l] = (red[0] + red[1]) + (red[2] + red[3]);
}

// ---------------------------------------------------------------------------
// Pass 1 (fused MLP+hist+place) — REVERTED to the measured-best structure
// (R5: 81us; later variants 85-89us). MLP blocks FIRST (overlap the scatter).
// Scatter: phase1 computes records into fixed LDS slots + per-local-bin
// counts (block spans <=2 images -> 64 local bins); wave0 reserves global
// ranges + exclusive-scans counts; phase3 reorders records bin-contiguously
// in LDS (rank via 2nd LDS atomic: any bijection works, integer accumulation
// is order-free); phase4 flushes LDS linearly -> coalesced global stores.
// ---------------------------------------------------------------------------
__global__ void __launch_bounds__(256)
place_kernel(const float* __restrict__ flow,
             const float* __restrict__ values,
             const int* __restrict__ inds,
             const float* __restrict__ rot,
             const float* __restrict__ shifts,
             const float* __restrict__ x,
             const float* __restrict__ w1T,
             float* __restrict__ hraw,
             unsigned* __restrict__ gcursor,
             unsigned long long* __restrict__ recs,
             int* __restrict__ qimg,
             int N, int TI, int IPB, int B) {
    int t = threadIdx.x;

    if (blockIdx.x < (unsigned)(B * LAT)) {     // ---- fused MLP path (FIRST) ----
        mlp_block(x, w1T, hraw, blockIdx.x);
        return;
    }
    int bid = blockIdx.x - B * LAT;

    __shared__ unsigned long long recL[SLOTS];   // 14336 B, item-order
    __shared__ unsigned long long recS[RECSL];   // 12544 B, bin-sorted
    __shared__ unsigned char bins8[SLOTS];       // 1792 B, local bin per slot
    __shared__ unsigned char binR8[RECSL];       // 1568 B, local bin per sorted pos
    __shared__ unsigned lcnt[64];                // local-bin counts (reused for ranks)
    __shared__ unsigned sbase[64];               // exclusive prefix of counts
    __shared__ unsigned lbase[64];               // global base per local bin

    if (t < 64) lcnt[t] = 0;
    __syncthreads();

    int s = bid * IPB;
    int e = min(s + IPB, TI);
    int b0 = s / N;              // block spans <= 2 batch values (IPB << N)
    int bBound = (b0 + 1) * N;

    // ---- phase 1: compute + count + stash in LDS (no carried registers) ----
    for (int k = 0; k < K_MAX; k++) {
        int slot = k * 256 + t;
        int i = s + slot;
        unsigned char bl = 0xFF;
        if (i < e) {
            int b = (i < bBound) ? b0 : b0 + 1;
            int n = i - b * N;
            int r, c; float f0, f1;
            compute_rc(flow, inds, rot, shifts, b, n, N, r, c, f0, f1);
            float amp = values[n];
            if (is_fast(r)) {
                int wr = (r + XS) & (XS - 1);
                int wc = c & (XS - 1);
                unsigned cv0 = (c >= -XS && c < XS) ? 1u : 0u;
                unsigned cv1 = (c + 1 >= -XS && c + 1 < XS) ? 1u : 0u;
                unsigned q0 = min(511u, (unsigned)(f0 * 512.0f + 0.5f));
                unsigned q1 = min(511u, (unsigned)(f1 * 512.0f + 0.5f));
                unsigned word = (unsigned)(wr & 7) | ((unsigned)wc << 3) |
                                (cv0 << 11) | (cv1 << 12) | (q0 << 13) | (q1 << 22);
                int local = (b - b0) * NG + (wr >> 3);   // [0,64)
                atomicAdd(&lcnt[local], 1u);
                recL[slot] = ((unsigned long long)__float_as_uint(amp) << 32) | word;
                bl = (unsigned char)local;
            } else {
                float g0 = 1.0f - f0, g1 = 1.0f - f1;
                int* Q = qimg + (size_t)b * XS2;
                corner_q(Q, r,     c,     amp * g0 * g1);
                corner_q(Q, r + 1, c,     amp * f0 * g1);
                corner_q(Q, r + 1, c + 1, amp * f0 * f1);
                corner_q(Q, r,     c + 1, amp * g0 * f1);
            }
        }
        bins8[slot] = bl;
    }
    __syncthreads();

    // ---- phase 2 (wave 0 only): reserve global ranges + exclusive scan ----
    if (t < 64) {
        unsigned cn = lcnt[t];
        unsigned gb = 0;
        if (cn) gb = atomicAdd(&gcursor[b0 * NG + t], cn);
        lbase[t] = gb;
        unsigned sc = cn;
#pragma unroll
        for (int off = 1; off < 64; off <<= 1) {
            unsigned nv = __shfl_up(sc, off, 64);
            if (t >= off) sc += nv;
        }
        sbase[t] = sc - cn;      // exclusive prefix
        lcnt[t] = 0;             // reuse as rank counters
    }
    __syncthreads();

    // ---- phase 3: reorder records bin-contiguously in LDS ----
    for (int k = 0; k < K_MAX; k++) {
        int slot = k * 256 + t;
        unsigned bl = bins8[slot];
        if (bl != 0xFFu) {
            unsigned r2 = atomicAdd(&lcnt[bl], 1u);
            unsigned q = sbase[bl] + r2;
            recS[q] = recL[slot];
            binR8[q] = (unsigned char)bl;
        }
    }
    __syncthreads();

    // ---- phase 4: linear LDS walk -> coalesced global stores ----
    unsigned total = sbase[63] + lcnt[63];
    for (unsigned p = t; p < total; p += 256) {
        unsigned long long rc = recS[p];
        unsigned bl = binR8[p];
        unsigned idx = lbase[bl] + (p - sbase[bl]);
        int bing = b0 * NG + (int)bl;
        if (idx < BINCAP) recs[(size_t)bing * BINCAP + idx] = rc;
        else rec_fallback_q(rc, bing, qimg);   // overflow (rare)
    }
}

// ---------------------------------------------------------------------------
// Pass 2: dual-parity 2x2 u64 cells -> exactly ONE ds_add_u64 per record.
// All-integer accumulation -> order-free -> deterministic.
// ---------------------------------------------------------------------------
__global__ void __launch_bounds__(256)
accum_kernel(const unsigned long long* __restrict__ recs,
             const unsigned* __restrict__ gcursor,
             float* __restrict__ reps,
             float* __restrict__ aprons, int B) {
    int bin = blockIdx.x >> 1, sp = blockIdx.x & 1;   // SPLIT=2
    int b = bin >> 5, g = bin & 31;
    __shared__ unsigned long long teven[BR * CELLW];  // 8 KB
    __shared__ unsigned long long todd[BR * CELLW];   // 8 KB
    int t = threadIdx.x;
    for (int k = t; k < BR * CELLW; k += 256) { teven[k] = 0ull; todd[k] = 0ull; }
    __syncthreads();

    unsigned cnt = min(gcursor[bin], (unsigned)BINCAP);
    unsigned lo = (unsigned)(((unsigned long long)cnt * sp) / SPLIT);
    unsigned hi = (unsigned)(((unsigned long long)cnt * (sp + 1)) / SPLIT);
    const unsigned long long* rb = recs + (size_t)bin * BINCAP;

    for (unsigned i = lo + t; i < hi; i += 256) {
        unsigned long long rc = rb[i];
        unsigned w = (unsigned)rc;
        float amp = __uint_as_float((unsigned)(rc >> 32));
        int rig = w & 7, wc = (w >> 3) & 255;
        float f0 = (float)((w >> 13) & 511) * (1.0f / 512.0f);
        float f1 = (float)((w >> 22) & 511) * (1.0f / 512.0f);
        float g0 = 1.0f - f0, g1 = 1.0f - f1;
        bool cv0 = (w >> 11) & 1, cv1 = (w >> 12) & 1;
        int q00 = cv0 ? __float2int_rn(amp * g0 * g1 * QS) : 0;  // (r,   cLo)
        int q10 = cv0 ? __float2int_rn(amp * f0 * g1 * QS) : 0;  // (r+1, cLo)
        int q01 = cv1 ? __float2int_rn(amp * g0 * f1 * QS) : 0;  // (r,   cHi)
        int q11 = cv1 ? __float2int_rn(amp * f0 * f1 * QS) : 0;  // (r+1, cHi)
        unsigned long long inc = pack4(q00, q10, q01, q11);
        unsigned long long* tile = (wc & 1) ? todd : teven;
        lds_add_u64(&tile[rig * CELLW + (wc >> 1)], inc);
    }
    __syncthreads();

    // flush: thread t = column c; carry r1-parts downward; row 8 -> apron.
    int c = t;
    int je = c >> 1;                                       // even tile cell
    int jo = (c & 1) ? (c >> 1) : (((c + 254) & 255) >> 1);// odd tile cell
    bool e_lo = (c & 1) == 0;   // even tile: this column is cLo (fields 0,1)
    bool o_lo = (c & 1) == 1;   // odd tile:  this column is cLo (fields 0,1)
    float* rep = reps + ((size_t)sp * B + b) * XS2;
    float carry = 0.0f;
#pragma unroll
    for (int rig = 0; rig < BR; rig++) {
        long long se = (long long)teven[rig * CELLW + je];
        int e0 = (int)(short)(se & 0xffff); se = (se - e0) >> 16;
        int e1 = (int)(short)(se & 0xffff); se = (se - e1) >> 16;
        int e2 = (int)(short)(se & 0xffff); se = (se - e2) >> 16;
        int e3 = (int)se;
        long long so = (long long)todd[rig * CELLW + jo];
        int o0 = (int)(short)(so & 0xffff); so = (so - o0) >> 16;
        int o1 = (int)(short)(so & 0xffff); so = (so - o1) >> 16;
        int o2 = (int)(short)(so & 0xffff); so = (so - o2) >> 16;
        int o3 = (int)so;
        float r0 = (e_lo ? (float)e0 : (float)e2) + (o_lo ? (float)o0 : (float)o2);
        float r1 = (e_lo ? (float)e1 : (float)e3) + (o_lo ? (float)o1 : (float)o3);
        rep[(g * BR + rig) * XS + c] = (carry + r0) * INVQS;
        carry = r1;
    }
    aprons[((size_t)bin * 2 + sp) * XS + c] = carry * INVQS;
}

// ---------------------------------------------------------------------------
// Fallback direct-scatter (tiny ws / unexpected shapes) — integer atomics.
// ---------------------------------------------------------------------------
__global__ void scatter_kernel(const float* __restrict__ flow,
                               const float* __restrict__ values,
                               const int* __restrict__ inds,
                               const float* __restrict__ rot,
                               const float* __restrict__ shifts,
                               int* __restrict__ qimg, int N) {
    int b = blockIdx.y;
    int n = blockIdx.x * blockDim.x + threadIdx.x;
    if (n >= N) return;
    int r, c; float f0, f1;
    compute_rc(flow, inds, rot, shifts, b, n, N, r, c, f0, f1);
    float amp = values[n];
    float g0 = 1.0f - f0, g1 = 1.0f - f1;
    int* Q = qimg + (size_t)b * XS2;
    corner_q(Q, r,     c,     amp * g0 * g1);
    corner_q(Q, r + 1, c,     amp * f0 * g1);
    corner_q(Q, r + 1, c + 1, amp * f0 * f1);
    corner_q(Q, r,     c + 1, amp * g0 * f1);
}

// fallback MLP: strided raw-w1 reads (no transpose available).
__global__ void mlp_kernel(const float* __restrict__ x,
                           const float* __restrict__ w1,
                           float* __restrict__ hraw) {
    int t = threadIdx.x;
    int id = blockIdx.x;
    int b = id / LAT, l = id - b * LAT;
    const float* xb = x + (size_t)b * XS2;
    float acc = 0.0f;
#pragma unroll 8
    for (int j = 0; j < 256; j++) {
        int e = j * 256 + t;
        acc += xb[e] * w1[(size_t)e * LAT + l];
    }
#pragma unroll
    for (int off = 32; off > 0; off >>= 1) acc += __shfl_down(acc, off);
    __shared__ float red[4];
    if ((t & 63) == 0) red[t >> 6] = acc;
    __syncthreads();
    if (t == 0) hraw[b * LAT + l] = (red[0] + red[1]) + (red[2] + red[3]);
}

// ---------------------------------------------------------------------------
// Fused combine + separable 3x3 blur + per-batch affine.
// S[row] = qimg/QS + rep0 + rep1 (+ aprons at row = 8k, k>=1).
// ---------------------------------------------------------------------------
__device__ __forceinline__ float S_load(const int* __restrict__ qimg,
                                        const float* __restrict__ reps,
                                        const float* __restrict__ aprons,
                                        int B, int b, int row, int c, int fast) {
    size_t o = (size_t)b * XS2 + row * XS + c;
    float v = (float)qimg[o] * INVQS;
    if (fast) {
        v += reps[o] + reps[(size_t)B * XS2 + o];
        if (row > 0 && (row & 7) == 0) {
            size_t bin = (size_t)b * NG + ((row >> 3) - 1);
            v += aprons[bin * 2 * XS + c] + aprons[(bin * 2 + 1) * XS + c];
        }
    }
    return v;
}

__global__ void blur_kernel(const int* __restrict__ qimg,
                            const float* __restrict__ reps,
                            const float* __restrict__ aprons,
                            const float* __restrict__ hraw,
                            const float* __restrict__ b1,
                            const float* __restrict__ w2,
                            const float* __restrict__ b2,
                            float* __restrict__ out, int B, int fast) {
    int b = blockIdx.y, r = blockIdx.x, c = threadIdx.x;
    float av = b2[0], bv = b2[1];
#pragma unroll
    for (int l = 0; l < LAT; l++) {
        float h = hraw[b * LAT + l] + b1[l];
        h = h > 0.0f ? h : 0.0f;
        av += h * w2[l * 2 + 0];
        bv += h * w2[l * 2 + 1];
    }
    const float g   = 0.6065306597126334f;   // exp(-0.5)
    const float inv = 1.0f / (1.0f + 2.0f * g);
    float up  = (r > 0)      ? S_load(qimg, reps, aprons, B, b, r - 1, c, fast) : 0.0f;
    float mid =                S_load(qimg, reps, aprons, B, b, r,     c, fast);
    float dn  = (r < XS - 1) ? S_load(qimg, reps, aprons, B, b, r + 1, c, fast) : 0.0f;
    float v = (g * (up + dn) + mid) * inv;
    __shared__ float row[XS + 2];
    row[c + 1] = v;
    if (c == 0) { row[0] = 0.0f; row[XS + 1] = 0.0f; }
    __syncthreads();
    float hh = (g * (row[c] + row[c + 2]) + v) * inv;
    out[(size_t)b * XS2 + (size_t)r * XS + c] = av * hh + bv;
}

extern "C" void kernel_launch(void* const* d_in, const int* in_sizes, int n_in,
                              void* d_out, int out_size, void* d_ws, size_t ws_size,
                              hipStream_t stream) {
    const float* flow   = (const float*)d_in[0];
    const float* x      = (const float*)d_in[1];
    const float* values = (const float*)d_in[2];
    const float* rot    = (const float*)d_in[3];
    const float* shifts = (const float*)d_in[4];
    const float* w1     = (const float*)d_in[5];
    const float* b1     = (const float*)d_in[6];
    const float* w2     = (const float*)d_in[7];
    const float* b2     = (const float*)d_in[8];
    const int*   inds   = (const int*)d_in[9];

    int N = in_sizes[2];          // values: (N,)
    int B = in_sizes[4] / 2;      // shifts: (B,2)
    int TI  = B * N;
    int IPB = (TI + P1 - 1) / P1;

    // workspace: qimg | hraw(256 f32) | gcursor(NBINS) | recs | reps | aprons | w1T
    size_t imgElems = (size_t)B * XS2;
    int*      qimg    = (int*)d_ws;
    float*    hraw    = (float*)(qimg + imgElems);        // 256 floats reserved
    unsigned* gcursor = (unsigned*)(hraw + 256);          // NBINS (512)
    unsigned long long* recs = (unsigned long long*)(gcursor + NBINS);  // NBINS*BINCAP
    float*    reps    = (float*)(recs + (size_t)NBINS * BINCAP);        // 2*B*XS2
    float*    aprons  = reps + 2 * imgElems;              // NBINS*2*XS
    float*    w1T     = aprons + (size_t)NBINS * 2 * XS;  // LAT*XS2
    size_t needed = (size_t)((char*)(w1T + (size_t)LAT * XS2) - (char*)d_ws);

    bool fast = (B * NG == NBINS) && (ws_size >= needed) && (IPB <= RECSL);

    // zero qimg + hraw + gcursor (bytes divisible by 16); + w1 transpose
    int n4 = (int)((imgElems * sizeof(int) + 1024 + NBINS * 4) / 16);
    init_kernel<<<fast ? (ZB + TB) : ZB, 256, 0, stream>>>((uint4*)d_ws, n4,
                                                           w1, w1T, fast ? 1 : 0);

    if (fast) {
        place_kernel<<<P1 + B * LAT, 256, 0, stream>>>(flow, values, inds, rot, shifts,
                                                       x, w1T, hraw, gcursor, recs, qimg,
                                                       N, TI, IPB, B);
        accum_kernel<<<NBINS * SPLIT, 256, 0, stream>>>(recs, gcursor, reps, aprons, B);
    } else {
        dim3 g1((N + 255) / 256, B);
        scatter_kernel<<<g1, 256, 0, stream>>>(flow, values, inds, rot, shifts, qimg, N);
        mlp_kernel<<<B * LAT, 256, 0, stream>>>(x, w1, hraw);
    }

    dim3 g3(XS, B);
    blur_kernel<<<g3, XS, 0, stream>>>(qimg, reps, aprons, hraw, b1, w2, b2,
                                       (float*)d_out, B, fast ? 1 : 0);
}